// Round 4
// baseline (308.761 us; speedup 1.0000x reference)
//
#include <hip/hip_runtime.h>

typedef unsigned char u8;
typedef float f32x4 __attribute__((ext_vector_type(4)));
typedef float f32x16 __attribute__((ext_vector_type(16)));

#define LL 4096
#define PSTR 136              // P row stride (bytes)
#define SCALE 16.0f           // x pre-scale before fp8
#define GSCALE (1.0f/256.0f)  // undo SCALE^2 on the gram
#define FREQC (-0.03597789207803197f)   // -ln(10000)/256

__device__ __forceinline__ long LCAST(uint2 v) { return __builtin_bit_cast(long, v); }

// ---------------- prep1: fp8 convert (x*16), row sumsq, tiled transpose ----------------
// 1024 blocks x 256 thr (4 blocks/CU, 4 waves/SIMD); block = 16 rows of one batch.
__global__ __launch_bounds__(256) void prep1(const float* __restrict__ x, u8* __restrict__ xbf,
                                             u8* __restrict__ xT, float* __restrict__ sq) {
  __shared__ u8 T[16 * 264];
  const int blk = blockIdx.x;
  const int b = blk >> 8, r0 = (blk & 255) << 4;
  const int tid = threadIdx.x;
  const long rowbase = (long)(b << 12) + r0;
  const float4* x4 = (const float4*)x + rowbase * 64;
  unsigned* xb4 = (unsigned*)xbf + rowbase * 64;
  #pragma unroll
  for (int i = 0; i < 4; ++i) {
    int idx = i * 256 + tid;                   // coalesced float4 stream
    float4 v = x4[idx];
    float s = v.x * v.x + v.y * v.y + v.z * v.z + v.w * v.w;
    #pragma unroll
    for (int o = 32; o; o >>= 1) s += __shfl_xor(s, o);
    if ((tid & 63) == 0) sq[rowbase + (idx >> 6)] = s;   // row == one wave
    int pk = __builtin_amdgcn_cvt_pk_fp8_f32(v.x * SCALE, v.y * SCALE, 0, false);
    pk = __builtin_amdgcn_cvt_pk_fp8_f32(v.z * SCALE, v.w * SCALE, pk, true);
    xb4[idx] = (unsigned)pk;
    *(unsigned*)(T + (idx >> 6) * 264 + (idx & 63) * 4) = (unsigned)pk;
  }
  __syncthreads();
  unsigned ob[4];
  #pragma unroll
  for (int jj = 0; jj < 4; ++jj) {
    unsigned b0 = T[(4 * jj + 0) * 264 + tid];
    unsigned b1 = T[(4 * jj + 1) * 264 + tid];
    unsigned b2 = T[(4 * jj + 2) * 264 + tid];
    unsigned b3 = T[(4 * jj + 3) * 264 + tid];
    ob[jj] = b0 | (b1 << 8) | (b2 << 16) | (b3 << 24);
  }
  *(uint4*)(xT + (((long)(b << 8) + tid) << 12) + r0) = *(uint4*)ob;
}

// ---------------- main fused kernel ----------------
// 512 blocks x 512 thr; 2 blocks/CU (4 waves/SIMD). Block = (batch, 32 Q rows), K-tile 128.
// mm1 (16x16x32 fp8, S^T): wave w -> K-strip 16w..16w+15 vs 32 Q (t=0,1).
// mm2 (32x32x16 fp8): wave w -> O[32][32w..32w+31], A = P from LDS, B = xT direct.
// K register-dbuf'd one iter ahead; V issued pre-barrier so it flies during the sync.
__global__ __launch_bounds__(512, 4) void tpe_main(
    const u8* __restrict__ xbf, const u8* __restrict__ xT,
    const float* __restrict__ sqv,
    const float* __restrict__ x, float* __restrict__ out) {
  __shared__ u8 Ps[2][32 * PSTR];
  __shared__ float lred[8][32];
  __shared__ float linv[32];

  const int tid = threadIdx.x;
  const int w = tid >> 6;
  const int lane = tid & 63;
  const int l15 = lane & 15, l31 = lane & 31;
  const int q4 = lane >> 4;   // 0..3
  const int q2 = lane >> 5;   // 0..1

  // XCD pinning: batch -> XCD pair; fp8 set (2 MB/batch) stays L2-hot
  const int blk = blockIdx.x;
  const int b = (blk & 7) >> 1;
  const int qt = ((blk >> 3) << 1) | (blk & 1);   // 0..127
  const int q0 = qt << 5;
  const long bL = (long)b * LL;

  // Q fragments (B-operand of mm1): 32 VGPRs
  uint2 qf[2][8];
  #pragma unroll
  for (int t = 0; t < 2; ++t) {
    const u8* qrow = xbf + ((bL + q0 + 16 * t + l15) << 8) + 8 * q4;
    #pragma unroll
    for (int s = 0; s < 8; ++s) qf[t][s] = *(const uint2*)(qrow + 32 * s);
  }
  float qa[2];
  #pragma unroll
  for (int t = 0; t < 2; ++t) qa[t] = -0.5f * sqv[bL + q0 + 16 * t + l15];

  f32x16 oacc;
  #pragma unroll
  for (int k = 0; k < 16; ++k) oacc[k] = 0.f;
  float rsacc[2] = {0.f, 0.f};

  u8* Ps0 = Ps[0];
  u8* Ps1 = Ps[1];
  const u8* vrow = xT + (((long)(b << 8) + 32 * w + l31) << 12) + 8 * q2;

  // prologue: iter-0 K + sqk
  uint2 kA[8], kB[8];
  float4 skA, skB;
  {
    const u8* kb = xbf + ((bL + 16 * w + l15) << 8) + 8 * q4;
    #pragma unroll
    for (int s = 0; s < 8; ++s) kA[s] = *(const uint2*)(kb + 32 * s);
    skA = *(const float4*)(sqv + bL + 16 * w + 4 * q4);
  }

#define TPE_ITER(KC, KN, SKC, SKN, IT, PBUF)                                                \
  {                                                                                         \
    const int j0 = (IT) << 7;                                                               \
    const int j1 = ((IT) < 31) ? (j0 + 128) : j0;                                           \
    { /* prefetch next-iter K + sqk */                                                      \
      const u8* kb = xbf + ((bL + j1 + 16 * w + l15) << 8) + 8 * q4;                        \
      _Pragma("unroll")                                                                     \
      for (int s = 0; s < 8; ++s) KN[s] = *(const uint2*)(kb + 32 * s);                     \
      SKN = *(const float4*)(sqv + bL + j1 + 16 * w + 4 * q4);                              \
    }                                                                                       \
    f32x4 sacc[2];                                                                          \
    _Pragma("unroll")                                                                       \
    for (int t = 0; t < 2; ++t) {                                                           \
      sacc[t][0] = 0.f; sacc[t][1] = 0.f; sacc[t][2] = 0.f; sacc[t][3] = 0.f;               \
    }                                                                                       \
    _Pragma("unroll")                                                                       \
    for (int s = 0; s < 8; ++s) {                                                           \
      long av = LCAST(KC[s]);                                                               \
      _Pragma("unroll")                                                                     \
      for (int t = 0; t < 2; ++t)                                                           \
        sacc[t] = __builtin_amdgcn_mfma_f32_16x16x32_fp8_fp8(av, LCAST(qf[t][s]), sacc[t], 0, 0, 0); \
    }                                                                                       \
    uint2 vf[8]; /* this-iter V: issued now, consumed after barrier */                      \
    _Pragma("unroll")                                                                       \
    for (int s = 0; s < 8; ++s) vf[s] = *(const uint2*)(vrow + j0 + 16 * s);                \
    _Pragma("unroll")                                                                       \
    for (int t = 0; t < 2; ++t) { /* lane: P[i=16t+l15][j=16w+4q4+0..3] */                  \
      float p0 = __expf(fminf(fmaf(sacc[t][0], GSCALE, qa[t] + SKC.x), 0.f));               \
      float p1 = __expf(fminf(fmaf(sacc[t][1], GSCALE, qa[t] + SKC.y), 0.f));               \
      float p2 = __expf(fminf(fmaf(sacc[t][2], GSCALE, qa[t] + SKC.z), 0.f));               \
      float p3 = __expf(fminf(fmaf(sacc[t][3], GSCALE, qa[t] + SKC.w), 0.f));               \
      rsacc[t] += (p0 + p1) + (p2 + p3);                                                    \
      int pk = __builtin_amdgcn_cvt_pk_fp8_f32(p0, p1, 0, false);                           \
      pk = __builtin_amdgcn_cvt_pk_fp8_f32(p2, p3, pk, true);                               \
      *(int*)((PBUF) + (16 * t + l15) * PSTR + 16 * w + 4 * q4) = pk;                       \
    }                                                                                       \
    __syncthreads();                                                                        \
    _Pragma("unroll")                                                                       \
    for (int s = 0; s < 8; ++s) {                                                           \
      long a0 = *(const long*)((PBUF) + l31 * PSTR + 16 * s + 8 * q2);                      \
      oacc = __builtin_amdgcn_mfma_f32_32x32x16_fp8_fp8(a0, LCAST(vf[s]), oacc, 0, 0, 0);   \
    }                                                                                       \
  }

  for (int it2 = 0; it2 < 16; ++it2) {
    TPE_ITER(kA, kB, skA, skB, 2 * it2, Ps0);
    TPE_ITER(kB, kA, skB, skA, 2 * it2 + 1, Ps1);
  }
#undef TPE_ITER

  // ---- epilogue: rowsum reduce; out = O/(16*l) + x + pe(inline) ----
  #pragma unroll
  for (int t = 0; t < 2; ++t) {
    float r = rsacc[t];
    r += __shfl_xor(r, 16);
    r += __shfl_xor(r, 32);
    if (lane < 16) lred[w][16 * t + lane] = r;
  }
  __syncthreads();
  if (tid < 32) {
    float s = 0.f;
    #pragma unroll
    for (int ww = 0; ww < 8; ++ww) s += lred[ww][tid];
    linv[tid] = 0.0625f / s;   // 1/16 undoes V pre-scale
  }
  __syncthreads();
  const int col = 32 * w + l31;
  const float freq = __expf((float)(col & ~1) * FREQC);
  #pragma unroll
  for (int reg = 0; reg < 16; ++reg) {
    int row = 4 * q2 + (reg & 3) + 8 * (reg >> 2);
    int l = q0 + row;
    float ang = (float)l * freq;
    float pv = (col & 1) ? __cosf(ang) : __sinf(ang);
    long off = ((bL + l) << 8) + col;
    out[off] = oacc[reg] * linv[row] + x[off] + pv;
  }
}

extern "C" void kernel_launch(void* const* d_in, const int* in_sizes, int n_in,
                              void* d_out, int out_size, void* d_ws, size_t ws_size,
                              hipStream_t stream) {
  const float* x = (const float*)d_in[0];
  float* out = (float*)d_out;
  char* ws = (char*)d_ws;
  u8* xbf = (u8*)ws;                       // 4,194,304 B  (fp8 x, [b][l][d])
  u8* xT = (u8*)(ws + 4194304);            // 4,194,304 B  (fp8 x^T, [b][d][l])
  float* sq = (float*)(ws + 8388608);      //    65,536 B
  prep1<<<1024, 256, 0, stream>>>(x, xbf, xT, sq);
  tpe_main<<<512, 512, 0, stream>>>(xbf, xT, sq, x, out);
}

// Round 5
// 149.460 us; speedup vs baseline: 2.0659x; 2.0659x over previous
//
#include <hip/hip_runtime.h>

typedef unsigned char u8;
typedef float f32x4 __attribute__((ext_vector_type(4)));
typedef float f32x16 __attribute__((ext_vector_type(16)));

#define LL 4096
#define PSTR 136              // P row stride (bytes), padded -> 0 conflicts (measured R3)
#define SCALE 16.0f           // x pre-scale before fp8
#define GSCALE (1.0f/256.0f)  // undo SCALE^2 on the gram
#define FREQC (-0.03597789207803197f)   // -ln(10000)/256

__device__ __forceinline__ long LCAST(uint2 v) { return __builtin_bit_cast(long, v); }

typedef __attribute__((address_space(3))) u8 lds_u8;
typedef __attribute__((address_space(1))) u8 glb_u8;
__device__ __forceinline__ void dma16(const u8* g, u8* l) {
  __builtin_amdgcn_global_load_lds((const glb_u8*)g, (lds_u8*)l, 16, 0, 0);
}

// ---------------- prep1: fp8 convert (x*16) with XOR-swizzled layouts ----------------
// xbf: row r (256 B): 8-B chunk c stored at ((c ^ (r&31))*8).
// xT : d-row (4096 B) split into 32 j-segments of 128 B; chunk c in segment at ((c ^ (d&15))*8).
// 1024 blocks x 256 thr; block = 16 rows of one batch.
__global__ __launch_bounds__(256) void prep1(const float* __restrict__ x, u8* __restrict__ xbf,
                                             u8* __restrict__ xT, float* __restrict__ sq) {
  __shared__ u8 T[16 * 264];
  const int blk = blockIdx.x;
  const int b = blk >> 8, r0 = (blk & 255) << 4;
  const int tid = threadIdx.x;
  const long rowbase = (long)(b << 12) + r0;
  const float4* x4 = (const float4*)x + rowbase * 64;
  unsigned* xb4 = (unsigned*)xbf + rowbase * 64;
  #pragma unroll
  for (int i = 0; i < 4; ++i) {
    int idx = i * 256 + tid;                   // coalesced float4 stream
    float4 v = x4[idx];
    float s = v.x * v.x + v.y * v.y + v.z * v.z + v.w * v.w;
    #pragma unroll
    for (int o = 32; o; o >>= 1) s += __shfl_xor(s, o);
    int row = idx >> 6, dw = idx & 63;
    if ((tid & 63) == 0) sq[rowbase + row] = s;      // row wave-uniform
    int pk = __builtin_amdgcn_cvt_pk_fp8_f32(v.x * SCALE, v.y * SCALE, 0, false);
    pk = __builtin_amdgcn_cvt_pk_fp8_f32(v.z * SCALE, v.w * SCALE, pk, true);
    int sdw = (((dw >> 1) ^ ((r0 + row) & 31)) << 1) | (dw & 1);
    xb4[row * 64 + sdw] = (unsigned)pk;
    *(unsigned*)(T + row * 264 + dw * 4) = (unsigned)pk;   // unswizzled staging
  }
  __syncthreads();
  unsigned ob[4];
  #pragma unroll
  for (int jj = 0; jj < 4; ++jj) {
    unsigned b0 = T[(4 * jj + 0) * 264 + tid];
    unsigned b1 = T[(4 * jj + 1) * 264 + tid];
    unsigned b2 = T[(4 * jj + 2) * 264 + tid];
    unsigned b3 = T[(4 * jj + 3) * 264 + tid];
    ob[jj] = b0 | (b1 << 8) | (b2 << 16) | (b3 << 24);
  }
  // thread tid owns d-row tid; j-range [r0, r0+16) = segment r0>>7, chunks cb, cb+1
  u8* drow = xT + ((((long)(b << 8) + tid) << 12)) + ((r0 >> 7) << 7);
  const int cb = (r0 & 127) >> 3, key = tid & 15;
  *(uint2*)(drow + ((cb ^ key) << 3)) = *(uint2*)(ob);
  *(uint2*)(drow + (((cb + 1) ^ key) << 3)) = *(uint2*)(ob + 2);
}

// ---------------- main fused kernel ----------------
// 256 blocks x 512 thr (8 waves, 1 block/CU, 2 waves/SIMD). Block = (batch, 64 Q rows).
// K-tile 128 / iter, 32 iters. K+V tiles DMA'd (global_load_lds w16) into dbuf LDS.
// mm1 (16x16x32 fp8, S^T): wave w -> j-strip 16w..16w+15 vs 64 Q (t=0..3).
// mm2 (32x32x16 fp8): wave w -> O[64][32w..32w+31]; A = P (LDS), B = V tile (LDS).
__global__ __launch_bounds__(512, 2) void tpe_main(
    const u8* __restrict__ xbf, const u8* __restrict__ xT,
    const float* __restrict__ sqv,
    const float* __restrict__ x, float* __restrict__ out) {
  __shared__ u8 Kt[2][32768];    // K tile, row-major 128x256, chunk-swizzled (as in xbf)
  __shared__ u8 Vt[2][32768];    // V tile, 256 d-rows x 128 j, chunk-swizzled (as in xT seg)
  __shared__ u8 Ps[64 * PSTR];
  __shared__ float lred[8][64];
  __shared__ float linv[64];

  const int tid = threadIdx.x;
  const int w = tid >> 6;
  const int lane = tid & 63;
  const int l15 = lane & 15, l31 = lane & 31;
  const int q4 = lane >> 4;   // 0..3
  const int q2 = lane >> 5;   // 0..1

  // XCD pinning: batch -> XCD pair; fp8 working set (2 MB/batch) stays L2-hot
  const int blk = blockIdx.x;
  const int b = (blk & 7) >> 1;
  const int qt = ((blk >> 3) << 1) | (blk & 1);
  const int q0 = qt << 6;
  const long bL = (long)b * LL;

  // Q fragments from swizzled xbf (prologue only)
  uint2 qf[4][8];
  #pragma unroll
  for (int t = 0; t < 4; ++t) {
    const int row = q0 + 16 * t + l15;
    const u8* qrow = xbf + ((bL + row) << 8);
    const int key = row & 31;
    #pragma unroll
    for (int s = 0; s < 8; ++s)
      qf[t][s] = *(const uint2*)(qrow + (((q4 + 4 * s) ^ key) << 3));
  }
  float qa[4];
  #pragma unroll
  for (int t = 0; t < 4; ++t) qa[t] = -0.5f * sqv[bL + q0 + 16 * t + l15];

  f32x16 oacc[2];
  #pragma unroll
  for (int rb = 0; rb < 2; ++rb)
    #pragma unroll
    for (int k = 0; k < 16; ++k) oacc[rb][k] = 0.f;
  float rsacc[4] = {0.f, 0.f, 0.f, 0.f};

  const u8* kbat = xbf + (bL << 8);                 // batch base of xbf
  const long vbat = ((long)(b << 8)) << 12;         // batch base of xT

  // prologue DMA: tile 0 -> buffer 0
  #pragma unroll
  for (int c = 0; c < 4; ++c) {
    int idx = c * 512 + tid;
    dma16(kbat + idx * 16, &Kt[0][idx * 16]);
  }
  #pragma unroll
  for (int c = 0; c < 4; ++c) {
    int idx = c * 512 + tid;
    int d = idx >> 3, part = idx & 7;
    dma16(xT + vbat + ((long)d << 12) + part * 16, &Vt[0][idx * 16]);
  }
  __syncthreads();   // drains vmcnt -> tile 0 resident

  for (int it = 0; it < 32; ++it) {
    const int cur = it & 1;
    const int j0 = it << 7;
    // async DMA next tile into the other buffer (in flight across mm1)
    if (it < 31) {
      const int g = it + 1;
      #pragma unroll
      for (int c = 0; c < 4; ++c) {
        int idx = c * 512 + tid;
        dma16(kbat + ((long)g << 15) + idx * 16, &Kt[cur ^ 1][idx * 16]);
      }
      #pragma unroll
      for (int c = 0; c < 4; ++c) {
        int idx = c * 512 + tid;
        int d = idx >> 3, part = idx & 7;
        dma16(xT + vbat + ((long)d << 12) + g * 128 + part * 16, &Vt[cur ^ 1][idx * 16]);
      }
    }
    float4 skv4 = *(const float4*)(sqv + bL + j0 + 16 * w + 4 * q4);
    // ---- mm1: S^T = K.Q^T from LDS K-tile ----
    const u8* kt = Kt[cur];
    const int krow = 16 * w + l15;
    const int kkey = krow & 31;
    f32x4 sacc[4];
    #pragma unroll
    for (int t = 0; t < 4; ++t) {
      sacc[t][0] = 0.f; sacc[t][1] = 0.f; sacc[t][2] = 0.f; sacc[t][3] = 0.f;
    }
    #pragma unroll
    for (int s = 0; s < 8; ++s) {
      uint2 kf = *(const uint2*)(kt + krow * 256 + (((q4 + 4 * s) ^ kkey) << 3));
      long av = LCAST(kf);
      #pragma unroll
      for (int t = 0; t < 4; ++t)
        sacc[t] = __builtin_amdgcn_mfma_f32_16x16x32_fp8_fp8(av, LCAST(qf[t][s]), sacc[t], 0, 0, 0);
    }
    // ---- P = exp(min(0, g - 0.5||q||^2 - 0.5||k||^2)) -> LDS ----
    #pragma unroll
    for (int t = 0; t < 4; ++t) {   // lane: P[i=16t+l15][j=16w+4q4+0..3]
      float p0 = __expf(fminf(fmaf(sacc[t][0], GSCALE, qa[t] + skv4.x), 0.f));
      float p1 = __expf(fminf(fmaf(sacc[t][1], GSCALE, qa[t] + skv4.y), 0.f));
      float p2 = __expf(fminf(fmaf(sacc[t][2], GSCALE, qa[t] + skv4.z), 0.f));
      float p3 = __expf(fminf(fmaf(sacc[t][3], GSCALE, qa[t] + skv4.w), 0.f));
      rsacc[t] += (p0 + p1) + (p2 + p3);
      int pk = __builtin_amdgcn_cvt_pk_fp8_f32(p0, p1, 0, false);
      pk = __builtin_amdgcn_cvt_pk_fp8_f32(p2, p3, pk, true);
      *(int*)(Ps + (16 * t + l15) * PSTR + 16 * w + 4 * q4) = pk;
    }
    __syncthreads();   // B1: P ready (also drains this iter's DMA, issued ~1 phase ago)
    // ---- mm2: O += P V from LDS ----
    const u8* vt = Vt[cur];
    const int vkey = l31 & 15;
    const u8* vrow = vt + (32 * w + l31) * 128;
    #pragma unroll
    for (int s = 0; s < 8; ++s) {
      uint2 bv = *(const uint2*)(vrow + (((2 * s + q2) ^ vkey) << 3));
      long bvl = LCAST(bv);
      #pragma unroll
      for (int rb = 0; rb < 2; ++rb) {
        long a = *(const long*)(Ps + (32 * rb + l31) * PSTR + 16 * s + 8 * q2);
        oacc[rb] = __builtin_amdgcn_mfma_f32_32x32x16_fp8_fp8(a, bvl, oacc[rb], 0, 0, 0);
      }
    }
    __syncthreads();   // B2: everyone done with tile `cur` and P before next overwrite
  }

  // ---- epilogue: rowsum reduce; out = O/(16*l) + x + pe(inline) ----
  #pragma unroll
  for (int t = 0; t < 4; ++t) {
    float r = rsacc[t];
    r += __shfl_xor(r, 16);
    r += __shfl_xor(r, 32);
    if (lane < 16) lred[w][16 * t + lane] = r;
  }
  __syncthreads();
  if (tid < 64) {
    float s = 0.f;
    #pragma unroll
    for (int ww = 0; ww < 8; ++ww) s += lred[ww][tid];
    linv[tid] = 0.0625f / s;   // 1/16 undoes V pre-scale
  }
  __syncthreads();
  const int col = 32 * w + l31;
  const float freq = __expf((float)(col & ~1) * FREQC);
  #pragma unroll
  for (int rb = 0; rb < 2; ++rb) {
    #pragma unroll
    for (int reg = 0; reg < 16; ++reg) {
      int row = 32 * rb + 4 * q2 + (reg & 3) + 8 * (reg >> 2);
      int l = q0 + row;
      float ang = (float)l * freq;
      float pv = (col & 1) ? __cosf(ang) : __sinf(ang);
      long off = ((bL + l) << 8) + col;
      out[off] = oacc[rb][reg] * linv[row] + x[off] + pv;
    }
  }
}

extern "C" void kernel_launch(void* const* d_in, const int* in_sizes, int n_in,
                              void* d_out, int out_size, void* d_ws, size_t ws_size,
                              hipStream_t stream) {
  const float* x = (const float*)d_in[0];
  float* out = (float*)d_out;
  char* ws = (char*)d_ws;
  u8* xbf = (u8*)ws;                       // 4,194,304 B  (fp8 x, swizzled rows)
  u8* xT = (u8*)(ws + 4194304);            // 4,194,304 B  (fp8 x^T, swizzled segments)
  float* sq = (float*)(ws + 8388608);      //    65,536 B
  prep1<<<1024, 256, 0, stream>>>(x, xbf, xT, sq);
  tpe_main<<<256, 512, 0, stream>>>(xbf, xT, sq, x, out);
}